// Round 4
// baseline (87.515 us; speedup 1.0000x reference)
//
#include <hip/hip_runtime.h>

// out[b][j] = table_bits[idx(b)][j]; idx(b) = MSB-first pack of (idx_bits[b][k] > 0).
// Streaming: 6 MiB idx read + 64 MiB out write -> ~11 us at the 6.1 TB/s fill pace.
// Table compressed to 64 uint64 masks via __ballot (no LDS table), single barrier,
// VALU bit->float expansion, nontemporal dwordx4 stores (native vec type for builtin).

#define ROWS 256   // batch rows per block: 256 rows x 64 floats = 64 KB out/block

typedef float nfloat4 __attribute__((ext_vector_type(4)));  // native vec: builtin-compatible

__global__ __launch_bounds__(256) void
spike_lut_kernel(const float* __restrict__ table,      // [64 rows][64 bits] float32
                 const int* __restrict__ idx_bits,     // [batch][6] int32
                 nfloat4* __restrict__ out4,           // [batch][16] float4
                 int batch) {
    __shared__ unsigned long long s_mask[64];   // bit j of s_mask[r] = table[r][j] > 0
    __shared__ int s_idx[ROWS];

    const int  tid  = threadIdx.x;
    const int  wave = tid >> 6;
    const int  lane = tid & 63;
    const long b0   = (long)blockIdx.x * ROWS;
    const bool full = (b0 + ROWS) <= batch;     // uniform per block

    // Phase A: compress table rows to 64-bit masks. Wave w handles rows 16w..16w+15;
    // lane j reads table[row][j] (coalesced dword), one __ballot per row.
    #pragma unroll
    for (int i = 0; i < 16; ++i) {
        const int row = wave * 16 + i;
        const float f = table[row * 64 + lane];
        const unsigned long long m = __ballot(f > 0.5f);
        if (lane == 0) s_mask[row] = m;
    }

    // Phase B: each thread packs its own row's 6-bit index (3x dwordx2/thread;
    // every byte of the 24B stride is consumed across the wave).
    {
        int idx = 0;
        const long b = b0 + tid;
        if (b < (long)batch) {
            const int* p = idx_bits + b * 6;
            #pragma unroll
            for (int k = 0; k < 6; ++k)
                idx = (idx << 1) | (p[k] > 0 ? 1 : 0);   // k=0 is MSB (weight 32)
        }
        s_idx[tid] = idx;
    }
    __syncthreads();   // the only barrier

    // Phase C: 16 lanes share one row -> both LDS reads are broadcasts; each lane
    // expands 4 mask bits to a float4 and streams it out (nontemporal dwordx4,
    // consecutive lanes at consecutive 16B addresses).
    if (full) {
        #pragma unroll
        for (int it = 0; it < 16; ++it) {
            const int g  = it * 256 + tid;
            const int bl = g >> 4;
            const int q  = g & 15;
            const unsigned int r = (unsigned int)(s_mask[s_idx[bl]] >> (q * 4));
            nfloat4 v;
            v.x = (r & 1u) ? 1.0f : 0.0f;
            v.y = (r & 2u) ? 1.0f : 0.0f;
            v.z = (r & 4u) ? 1.0f : 0.0f;
            v.w = (r & 8u) ? 1.0f : 0.0f;
            __builtin_nontemporal_store(v, &out4[(b0 + bl) * 16 + q]);
        }
    } else {
        #pragma unroll
        for (int it = 0; it < 16; ++it) {
            const int g  = it * 256 + tid;
            const int bl = g >> 4;
            const int q  = g & 15;
            if (b0 + bl < batch) {
                const unsigned int r = (unsigned int)(s_mask[s_idx[bl]] >> (q * 4));
                nfloat4 v;
                v.x = (r & 1u) ? 1.0f : 0.0f;
                v.y = (r & 2u) ? 1.0f : 0.0f;
                v.z = (r & 4u) ? 1.0f : 0.0f;
                v.w = (r & 8u) ? 1.0f : 0.0f;
                __builtin_nontemporal_store(v, &out4[(b0 + bl) * 16 + q]);
            }
        }
    }
}

extern "C" void kernel_launch(void* const* d_in, const int* in_sizes, int n_in,
                              void* d_out, int out_size, void* d_ws, size_t ws_size,
                              hipStream_t stream) {
    const float* table    = (const float*)d_in[0];   // [64,64] float32
    const int*   idx_bits = (const int*)d_in[1];     // [batch,6] int32
    nfloat4*     out4     = (nfloat4*)d_out;

    const int batch  = in_sizes[1] / 6;
    const int blocks = (batch + ROWS - 1) / ROWS;

    spike_lut_kernel<<<blocks, 256, 0, stream>>>(table, idx_bits, out4, batch);
}